// Round 2
// baseline (134.749 us; speedup 1.0000x reference)
//
#include <hip/hip_runtime.h>
#include <hip/hip_bf16.h>

// Flash-style masked dot-product attention. fp32 I/O, bf16 MFMA compute.
// n=32, s=2048, d=64.
// R9 vs R8 (51us attn): R8 was latency-bound (122K cyc vs 38K max-pipe;
// occupancy 16.5%) -- barrier-coupled staging killed overlap. R9 removes
// the main-loop LDS + barriers ENTIRELY:
//  1) prepass writes K and V in MFMA-FRAGMENT order (per 64-key tile: 8
//     frags x 64 lanes x 16B for QK-A and for PV-B). Main loop reads frags
//     as coalesced global_load_dwordx4 straight into MFMA operands; tiles
//     are L2-resident (same-batch blocks have consecutive blockIdx).
//  2) waves fully independent: (qg = q-half, pg = key-tile parity); no
//     __syncthreads in the loop; epilogue combines pg partials via LDS once.
//  3) row-sum l via VALU reduce + permlane32_swap instead of ones-MFMA
//     (-20% MFMA work, -20 VGPR); in-register P exchange kept from R8.
// Floor: L2 540MB / 34.5 TB/s ~= 16us; MFMA 17K cyc/CU ~= 7us.
// Kept: LPT snake, fixed-max softmax p=exp2(S), Q pre-scaled 0.125*log2e.
// 32x32x16 bf16 layouts: A[m=l31][k=hi*8+j]  B[k=hi*8+j][n=l31]
//   C/D: col=l31, row=(r&3)+8*(r>>2)+4*hi.

typedef short bf16x8 __attribute__((ext_vector_type(8)));
typedef float f32x4  __attribute__((ext_vector_type(4)));
typedef float f32x16 __attribute__((ext_vector_type(16)));
typedef unsigned int u32;
typedef u32 u32x4 __attribute__((ext_vector_type(4)));

#define SEQ 2048
#define DH 64
#define BK 64
#define LDSP 72
#define FRAG 512          // shorts per frag (64 lanes x 8)
#define TILE_SH 4096      // shorts per tile blob (8 frags)
#define SCLQ 0.18033688011112042f   // (1/sqrt(64)) * log2(e)

static __device__ __forceinline__ short f2bf(float f) {
    unsigned u = __float_as_uint(f);
    return (short)((u + 0x7FFFu + ((u >> 16) & 1u)) >> 16);   // RNE, finite
}
static __device__ __forceinline__ u32 pk2bf(float lo, float hi) {
    __hip_bfloat162 h = __float22bfloat162_rn(float2{lo, hi});  // v_cvt_pk_bf16_f32
    return *(u32*)&h;
}
// exchanges: a[l>=32] <- b[l-32] ; b[l<32] <- a[l+32]
static __device__ __forceinline__ void pl32swap(u32& a, u32& b) {
    asm volatile("v_permlane32_swap_b32 %0, %1" : "+v"(a), "+v"(b));
}

// ---- pre-pass: K,V fp32 -> bf16 in MFMA-fragment order ----
// KF[b][t][f=st*2+kh][lane][j] = K[b][t*64 + kh*32 + (lane&31)][st*16 + (lane>>5)*8 + j]
// VF[b][t][f=ks*2+dh][lane][j] = V[b][t*64 + ks*16 + (lane>>5)*8 + j][dh*32 + (lane&31)]
__global__ __launch_bounds__(256, 4)
void prepass(const float* __restrict__ K, const float* __restrict__ V,
             short* __restrict__ KF, short* __restrict__ VF)
{
    __shared__ short T[DH][LDSP];   // V^T tile [dim][key]

    const int tid  = threadIdx.x;
    const int wave = tid >> 6;
    const int lane = tid & 63;
    const int b  = blockIdx.x & 31;
    const int t  = blockIdx.x >> 5;
    const int k0 = t * BK;
    const size_t bo = (size_t)b * SEQ * DH;
    const size_t tb = (size_t)(b * 32 + t) * TILE_SH;

    // K -> KF frags (reads cached, stores perfectly coalesced)
    const float* Ks = K + bo + (size_t)k0 * DH;
    short* Kd = KF + tb;
    #pragma unroll
    for (int h = 0; h < 2; ++h) {
        const int c = tid + h * 256;           // 512 chunks
        const int f = c >> 6;
        const int row = (f & 1) * 32 + (c & 31);
        const int col = (f >> 1) * 16 + ((c >> 5) & 1) * 8;
        f32x4 a = *(const f32x4*)(Ks + row * DH + col);
        f32x4 d = *(const f32x4*)(Ks + row * DH + col + 4);
        u32x4 o;
        o[0] = pk2bf(a[0], a[1]); o[1] = pk2bf(a[2], a[3]);
        o[2] = pk2bf(d[0], d[1]); o[3] = pk2bf(d[2], d[3]);
        *(u32x4*)(Kd + c * 8) = o;
    }

    // V tile -> LDS transposed
    #pragma unroll
    for (int h = 0; h < 2; ++h) {
        const int d0 = wave * 8 + h * 32;
        const float* src = V + bo + (size_t)(k0 + lane) * DH + d0;
        f32x4 va = *(const f32x4*)(src);
        f32x4 vb = *(const f32x4*)(src + 4);
        #pragma unroll
        for (int j = 0; j < 4; ++j) {
            T[d0 + j][lane]     = f2bf(va[j]);
            T[d0 + 4 + j][lane] = f2bf(vb[j]);
        }
    }
    __syncthreads();

    // T -> VF frags (LDS 16B reads, stores coalesced)
    short* Vd = VF + tb;
    #pragma unroll
    for (int h = 0; h < 2; ++h) {
        const int c = tid + h * 256;
        const int f = c >> 6;
        const int trow = (f & 1) * 32 + (c & 31);          // dh*32 + l31
        const int tcol = (f >> 1) * 16 + ((c >> 5) & 1) * 8; // ks*16 + hi*8
        *(bf16x8*)(Vd + c * 8) = *(const bf16x8*)(&T[trow][tcol]);
    }
}

// ---------------- main kernel ----------------
template <bool PRE>
__global__ __launch_bounds__(256, 4)
void attn_fwd(const float* __restrict__ Q,
              const float* __restrict__ Kf, const float* __restrict__ Vf,
              const short* __restrict__ KF, const short* __restrict__ VF,
              const int* __restrict__ VL, float* __restrict__ O)
{
    __shared__ __align__(16) float Red[2][64][44];   // pg=1 dump: 32 oacc + L
    __shared__ int Rsort[32];

    const int tid  = threadIdx.x;
    const int wave = tid >> 6;
    const int lane = tid & 63;
    const int qg   = wave & 1;     // query half: q in [qg*32, qg*32+32)
    const int pg   = wave >> 1;    // key-tile parity
    const int hi   = lane >> 5;
    const int l31  = lane & 31;

    // LPT snake: co-resident blocks get batch ranks {c,15-c,16+c,31-c}
    if (tid < 32) {
        const int nv = (VL[tid] + BK - 1) >> 6;
        int rank = 0;
        for (int jj = 0; jj < 32; ++jj) {
            const int nj = (VL[jj] + BK - 1) >> 6;
            rank += (nj > nv) || (nj == nv && jj < tid);
        }
        Rsort[rank] = tid;
    }
    __syncthreads();

    const int jb = blockIdx.x & 255;
    const int sl = blockIdx.x >> 8;
    const int c8 = jb >> 5;
    const int qt = jb & 31;
    const int rk = (sl == 0) ? c8 : (sl == 1) ? (15 - c8)
                 : (sl == 2) ? (16 + c8) : (31 - c8);
    int b = Rsort[rk];
    b = __builtin_amdgcn_readfirstlane(b);

    const int vl  = __builtin_amdgcn_readfirstlane(VL[b]);
    const int nkt = (vl + BK - 1) >> 6;

    const size_t bo = (size_t)b * SEQ * DH;
    const short* KFb = KF + (size_t)b * 32 * TILE_SH;
    const short* VFb = VF + (size_t)b * 32 * TILE_SH;
    const float* Kf32 = Kf + bo;
    const float* Vf32 = Vf + bo;

    // Q B-frags, pre-scaled: p = exp2(S) = e^{qk/8}
    const int qrow = qt * 64 + qg * 32 + l31;
    bf16x8 aq[4];
    {
        const float* qp = Q + bo + (size_t)qrow * DH + hi * 8;
        #pragma unroll
        for (int st = 0; st < 4; ++st) {
            f32x4 a = *(const f32x4*)(qp + st * 16);
            f32x4 c = *(const f32x4*)(qp + st * 16 + 4);
            #pragma unroll
            for (int j = 0; j < 4; ++j) {
                aq[st][j]     = f2bf(a[j] * SCLQ);
                aq[st][j + 4] = f2bf(c[j] * SCLQ);
            }
        }
    }

    f32x16 oacc0, oacc1;
    #pragma unroll
    for (int i = 0; i < 16; ++i) { oacc0[i] = 0.f; oacc1[i] = 0.f; }
    float Lrun = 0.f;

    const int lo8 = lane * 8;

    for (int kt = pg; kt < nkt; kt += 2) {
        const int k0 = kt * BK;
        const short* kf = KFb + (size_t)kt * TILE_SH;
        const short* vf = VFb + (size_t)kt * TILE_SH;

        auto ldA = [&](int f) -> bf16x8 {
            if constexpr (PRE) {
                return *(const bf16x8*)(kf + f * FRAG + lo8);
            } else {
                const int st = f >> 1, kh = f & 1;
                const float* p = Kf32 + (size_t)(k0 + kh * 32 + l31) * DH + st * 16 + hi * 8;
                f32x4 x = *(const f32x4*)p;
                f32x4 y = *(const f32x4*)(p + 4);
                bf16x8 r;
                #pragma unroll
                for (int j = 0; j < 4; ++j) { r[j] = f2bf(x[j]); r[j + 4] = f2bf(y[j]); }
                return r;
            }
        };
        auto ldV = [&](int f) -> bf16x8 {
            if constexpr (PRE) {
                return *(const bf16x8*)(vf + f * FRAG + lo8);
            } else {
                const int ks = f >> 1, dh = f & 1;
                bf16x8 r;
                #pragma unroll
                for (int j = 0; j < 8; ++j)
                    r[j] = f2bf(Vf32[(size_t)(k0 + ks * 16 + hi * 8 + j) * DH + dh * 32 + l31]);
                return r;
            }
        };

        // ---- S^T = K * Q^T : rows = keys, cols = q (l31); staggered loads ----
        f32x16 s0, s1;
        #pragma unroll
        for (int i = 0; i < 16; ++i) { s0[i] = 0.f; s1[i] = 0.f; }

        __builtin_amdgcn_s_setprio(1);
        bf16x8 A00 = ldA(0), A01 = ldA(1);
        bf16x8 A10 = ldA(2), A11 = ldA(3);
        s0 = __builtin_amdgcn_mfma_f32_32x32x16_bf16(A00, aq[0], s0, 0, 0, 0);
        s1 = __builtin_amdgcn_mfma_f32_32x32x16_bf16(A01, aq[0], s1, 0, 0, 0);
        bf16x8 A20 = ldA(4), A21 = ldA(5);
        s0 = __builtin_amdgcn_mfma_f32_32x32x16_bf16(A10, aq[1], s0, 0, 0, 0);
        s1 = __builtin_amdgcn_mfma_f32_32x32x16_bf16(A11, aq[1], s1, 0, 0, 0);
        bf16x8 A30 = ldA(6), A31 = ldA(7);
        s0 = __builtin_amdgcn_mfma_f32_32x32x16_bf16(A20, aq[2], s0, 0, 0, 0);
        s1 = __builtin_amdgcn_mfma_f32_32x32x16_bf16(A21, aq[2], s1, 0, 0, 0);
        s0 = __builtin_amdgcn_mfma_f32_32x32x16_bf16(A30, aq[3], s0, 0, 0, 0);
        s1 = __builtin_amdgcn_mfma_f32_32x32x16_bf16(A31, aq[3], s1, 0, 0, 0);
        __builtin_amdgcn_s_setprio(0);

        // early V loads: latency hides under softmax VALU work
        bf16x8 V00 = ldV(0), V01 = ldV(1);
        bf16x8 V10 = ldV(2), V11 = ldV(3);

        // ---- p = exp2(S); mask by key row on boundary tile only ----
        if (k0 + BK <= vl) {
            #pragma unroll
            for (int r = 0; r < 16; ++r) {
                s0[r] = __builtin_amdgcn_exp2f(s0[r]);
                s1[r] = __builtin_amdgcn_exp2f(s1[r]);
            }
        } else {
            #pragma unroll
            for (int r = 0; r < 16; ++r) {
                const int krow = k0 + (r & 3) + 8 * (r >> 2) + 4 * hi;
                s0[r] = (krow < vl)      ? __builtin_amdgcn_exp2f(s0[r]) : 0.f;
                s1[r] = (krow + 32 < vl) ? __builtin_amdgcn_exp2f(s1[r]) : 0.f;
            }
        }

        // ---- l[q=l31] += sum over this tile's keys (VALU + permlane) ----
        {
            float ls = 0.f;
            #pragma unroll
            for (int r = 0; r < 16; ++r) ls += s0[r] + s1[r];
            u32 a = __float_as_uint(ls), c = a;
            pl32swap(a, c);          // a+c = own + cross-hi partner, all lanes
            Lrun += __uint_as_float(a) + __uint_as_float(c);
        }

        // ---- pack to bf16 pairs, in-register P exchange -> PV A-frags ----
        u32 pk0[8], pk1[8];
        #pragma unroll
        for (int i = 0; i < 8; ++i) {
            pk0[i] = pk2bf(s0[2 * i], s0[2 * i + 1]);
            pk1[i] = pk2bf(s1[2 * i], s1[2 * i + 1]);
        }
        bf16x8 ap[4];
        #pragma unroll
        for (int t = 0; t < 2; ++t) {
            u32 x0 = pk0[4 * t], x1 = pk0[4 * t + 1];
            u32 x2 = pk0[4 * t + 2], x3 = pk0[4 * t + 3];
            pl32swap(x0, x2); pl32swap(x1, x3);
            u32x4 w; w[0] = x0; w[1] = x1; w[2] = x2; w[3] = x3;
            ap[t] = *(bf16x8*)&w;
            u32 y0 = pk1[4 * t], y1 = pk1[4 * t + 1];
            u32 y2 = pk1[4 * t + 2], y3 = pk1[4 * t + 3];
            pl32swap(y0, y2); pl32swap(y1, y3);
            u32x4 v; v[0] = y0; v[1] = y1; v[2] = y2; v[3] = y3;
            ap[2 + t] = *(bf16x8*)&v;
        }

        // ---- O += P V ----
        __builtin_amdgcn_s_setprio(1);
        oacc0 = __builtin_amdgcn_mfma_f32_32x32x16_bf16(ap[0], V00, oacc0, 0, 0, 0);
        oacc1 = __builtin_amdgcn_mfma_f32_32x32x16_bf16(ap[0], V01, oacc1, 0, 0, 0);
        bf16x8 V20 = ldV(4), V21 = ldV(5);
        oacc0 = __builtin_amdgcn_mfma_f32_32x32x16_bf16(ap[1], V10, oacc0, 0, 0, 0);
        oacc1 = __builtin_amdgcn_mfma_f32_32x32x16_bf16(ap[1], V11, oacc1, 0, 0, 0);
        bf16x8 V30 = ldV(6), V31 = ldV(7);
        oacc0 = __builtin_amdgcn_mfma_f32_32x32x16_bf16(ap[2], V20, oacc0, 0, 0, 0);
        oacc1 = __builtin_amdgcn_mfma_f32_32x32x16_bf16(ap[2], V21, oacc1, 0, 0, 0);
        oacc0 = __builtin_amdgcn_mfma_f32_32x32x16_bf16(ap[3], V30, oacc0, 0, 0, 0);
        oacc1 = __builtin_amdgcn_mfma_f32_32x32x16_bf16(ap[3], V31, oacc1, 0, 0, 0);
        __builtin_amdgcn_s_setprio(0);
    }

    // ---- epilogue: combine pg partials (one barrier), O = sum/l ----
    float* rp = &Red[qg][lane][0];
    if (pg == 1) {
        #pragma unroll
        for (int wd = 0; wd < 4; ++wd) {
            f32x4 t0, t1;
            #pragma unroll
            for (int i = 0; i < 4; ++i) { t0[i] = oacc0[wd * 4 + i]; t1[i] = oacc1[wd * 4 + i]; }
            *(f32x4*)(rp + wd * 4)      = t0;
            *(f32x4*)(rp + 16 + wd * 4) = t1;
        }
        rp[32] = Lrun;
    }
    __syncthreads();
    if (pg == 0) {
        f32x4 p0[4], p1[4];
        #pragma unroll
        for (int wd = 0; wd < 4; ++wd) {
            p0[wd] = *(const f32x4*)(rp + wd * 4);
            p1[wd] = *(const f32x4*)(rp + 16 + wd * 4);
        }
        const float Lq = Lrun + rp[32];
        #pragma unroll
        for (int r = 0; r < 16; ++r) {
            const int rb = (r & 3) + 8 * (r >> 2) + 4 * hi;
            const float inv = 1.0f / __shfl(Lq, rb);
            const int row = qt * 64 + qg * 32 + rb;
            O[bo + (size_t)row * DH + l31]      = (oacc0[r] + p0[r >> 2][r & 3]) * inv;
            O[bo + (size_t)row * DH + 32 + l31] = (oacc1[r] + p1[r >> 2][r & 3]) * inv;
        }
    }
}

extern "C" void kernel_launch(void* const* d_in, const int* in_sizes, int n_in,
                              void* d_out, int out_size, void* d_ws, size_t ws_size,
                              hipStream_t stream) {
    const float* Q  = (const float*)d_in[0];
    const float* K  = (const float*)d_in[1];
    const float* V  = (const float*)d_in[2];
    const int*   VL = (const int*)d_in[3];
    float* O = (float*)d_out;

    const size_t nel = (size_t)32 * 32 * TILE_SH;   // shorts per array
    const size_t need = 2 * nel * sizeof(short);    // 16 MB (ws >= 68MB proven R5)
    if (ws_size >= need) {
        short* KF = (short*)d_ws;
        short* VF = KF + nel;
        prepass<<<dim3(1024), dim3(256), 0, stream>>>(K, V, KF, VF);
        attn_fwd<true><<<dim3(1024), dim3(256), 0, stream>>>(Q, K, V, KF, VF, VL, O);
    } else {
        attn_fwd<false><<<dim3(1024), dim3(256), 0, stream>>>(Q, K, V, nullptr, nullptr, VL, O);
    }
}

// Round 5
// 129.929 us; speedup vs baseline: 1.0371x; 1.0371x over previous
//
#include <hip/hip_runtime.h>
#include <hip/hip_bf16.h>

// Flash-style masked dot-product attention. fp32 I/O, bf16 MFMA compute.
// n=32, s=2048, d=64.
// R12 vs R11 (failed, absmax~2): R10 and R11 failed identically despite
// completely different merge structures; per-wave compute is verbatim R9
// (passed). Only factor common to exactly the failing pair:
// __launch_bounds__(256,8), which pins VGPR to 64 HARD against a live set
// far above 64 (forced spill codegen around permlane asm / f32x16).
// R12 = R11 structure with __launch_bounds__(256,4) (R9's proven setting;
// R9 naturally compiled to VGPR=64 under it). HW packs blocks by ACTUAL
// VGPR/LDS, so if this lands at 64 VGPR the scheduler still gives
// 8 blocks/CU x 4 waves = 32 waves/CU (grid 2048, LDS 18.6KB <= 20KB).
// Structure (from R11):
//  - 2048 blocks = 32 batches x 64 q-groups; each block owns 32 QUERIES.
//  - 4 waves/block split keys 4-way (kt = wave, wave+4, ...): independent
//    flash partials, merged in-block by a 2-round LDS tree (3 barriers,
//    epilogue only, fixed-order fp32 adds -> deterministic).
//  - block->batch: rk = blockIdx>>6 over LPT-sorted ranks (balanced);
//    64 consecutive same-batch blocks co-dispatch -> share K/V in XCD L2.
// Kept from R9: frag-order prepass (no main-loop LDS/barriers), in-register
// P exchange via permlane32_swap, VALU l-reduce, fixed-max softmax
// p = exp2(S) with Q pre-scaled by 0.125*log2e.
// 32x32x16 bf16 layouts: A[m=l31][k=hi*8+j]  B[k=hi*8+j][n=l31]
//   C/D: col=l31, row=(r&3)+8*(r>>2)+4*hi.

typedef short bf16x8 __attribute__((ext_vector_type(8)));
typedef float f32x4  __attribute__((ext_vector_type(4)));
typedef float f32x16 __attribute__((ext_vector_type(16)));
typedef unsigned int u32;
typedef u32 u32x4 __attribute__((ext_vector_type(4)));

#define SEQ 2048
#define DH 64
#define BK 64
#define LDSP 72
#define FRAG 512          // shorts per frag (64 lanes x 8)
#define TILE_SH 4096      // shorts per tile blob (8 frags)
#define PSTRIDE 36        // f32 per partial row (32 O + 1 L + pad)
#define SCLQ 0.18033688011112042f   // (1/sqrt(64)) * log2(e)

static __device__ __forceinline__ short f2bf(float f) {
    unsigned u = __float_as_uint(f);
    return (short)((u + 0x7FFFu + ((u >> 16) & 1u)) >> 16);   // RNE, finite
}
static __device__ __forceinline__ u32 pk2bf(float lo, float hi) {
    __hip_bfloat162 h = __float22bfloat162_rn(float2{lo, hi});  // v_cvt_pk_bf16_f32
    return *(u32*)&h;
}
// exchanges: a[l>=32] <- b[l-32] ; b[l<32] <- a[l+32]
static __device__ __forceinline__ void pl32swap(u32& a, u32& b) {
    asm volatile("v_permlane32_swap_b32 %0, %1" : "+v"(a), "+v"(b));
}

// ---- pre-pass: K,V fp32 -> bf16 in MFMA-fragment order ----
// KF[b][t][f=st*2+kh][lane][j] = K[b][t*64 + kh*32 + (lane&31)][st*16 + (lane>>5)*8 + j]
// VF[b][t][f=ks*2+dh][lane][j] = V[b][t*64 + ks*16 + (lane>>5)*8 + j][dh*32 + (lane&31)]
__global__ __launch_bounds__(256, 4)
void prepass(const float* __restrict__ K, const float* __restrict__ V,
             short* __restrict__ KF, short* __restrict__ VF)
{
    __shared__ short T[DH][LDSP];   // V^T tile [dim][key]

    const int tid  = threadIdx.x;
    const int wave = tid >> 6;
    const int lane = tid & 63;
    const int b  = blockIdx.x & 31;
    const int t  = blockIdx.x >> 5;
    const int k0 = t * BK;
    const size_t bo = (size_t)b * SEQ * DH;
    const size_t tb = (size_t)(b * 32 + t) * TILE_SH;

    // K -> KF frags (reads cached, stores perfectly coalesced)
    const float* Ks = K + bo + (size_t)k0 * DH;
    short* Kd = KF + tb;
    #pragma unroll
    for (int h = 0; h < 2; ++h) {
        const int c = tid + h * 256;           // 512 chunks
        const int f = c >> 6;
        const int row = (f & 1) * 32 + (c & 31);
        const int col = (f >> 1) * 16 + ((c >> 5) & 1) * 8;
        f32x4 a = *(const f32x4*)(Ks + row * DH + col);
        f32x4 d = *(const f32x4*)(Ks + row * DH + col + 4);
        u32x4 o;
        o[0] = pk2bf(a[0], a[1]); o[1] = pk2bf(a[2], a[3]);
        o[2] = pk2bf(d[0], d[1]); o[3] = pk2bf(d[2], d[3]);
        *(u32x4*)(Kd + c * 8) = o;
    }

    // V tile -> LDS transposed
    #pragma unroll
    for (int h = 0; h < 2; ++h) {
        const int d0 = wave * 8 + h * 32;
        const float* src = V + bo + (size_t)(k0 + lane) * DH + d0;
        f32x4 va = *(const f32x4*)(src);
        f32x4 vb = *(const f32x4*)(src + 4);
        #pragma unroll
        for (int j = 0; j < 4; ++j) {
            T[d0 + j][lane]     = f2bf(va[j]);
            T[d0 + 4 + j][lane] = f2bf(vb[j]);
        }
    }
    __syncthreads();

    // T -> VF frags (LDS 16B reads, stores coalesced)
    short* Vd = VF + tb;
    #pragma unroll
    for (int h = 0; h < 2; ++h) {
        const int c = tid + h * 256;
        const int f = c >> 6;
        const int trow = (f & 1) * 32 + (c & 31);            // dh*32 + l31
        const int tcol = (f >> 1) * 16 + ((c >> 5) & 1) * 8; // ks*16 + hi*8
        *(bf16x8*)(Vd + c * 8) = *(const bf16x8*)(&T[trow][tcol]);
    }
}

// ---------------- main kernel ----------------
// Block = 32 queries; 4 waves split keys 4-way; in-block tree combine.
template <bool PRE>
__global__ __launch_bounds__(256, 4)
void attn_fwd(const float* __restrict__ Q,
              const float* __restrict__ Kf, const float* __restrict__ Vf,
              const short* __restrict__ KF, const short* __restrict__ VF,
              const int* __restrict__ VL, float* __restrict__ O)
{
    __shared__ __align__(16) float Red[2][64][PSTRIDE];  // tree-combine slots
    __shared__ int Rsort[32];

    const int tid  = threadIdx.x;
    const int wave = tid >> 6;     // = key-split group
    const int lane = tid & 63;
    const int hi   = lane >> 5;
    const int l31  = lane & 31;

    // LPT: rank batches by descending tile count
    if (tid < 32) {
        const int nv = (VL[tid] + BK - 1) >> 6;
        int rank = 0;
        for (int jj = 0; jj < 32; ++jj) {
            const int nj = (VL[jj] + BK - 1) >> 6;
            rank += (nj > nv) || (nj == nv && jj < tid);
        }
        Rsort[rank] = tid;
    }
    __syncthreads();

    const int qq = blockIdx.x & 63;        // q-group within batch (32 q each)
    const int rk = blockIdx.x >> 6;        // batch rank [0,32)
    int b = Rsort[rk];
    b = __builtin_amdgcn_readfirstlane(b);

    const int vl  = __builtin_amdgcn_readfirstlane(VL[b]);
    const int nkt = (vl + BK - 1) >> 6;

    const size_t bo = (size_t)b * SEQ * DH;
    const short* KFb = KF + (size_t)b * 32 * TILE_SH;
    const short* VFb = VF + (size_t)b * 32 * TILE_SH;
    const float* Kf32 = Kf + bo;
    const float* Vf32 = Vf + bo;

    // Q B-frags, pre-scaled: p = exp2(S) = e^{qk/8}
    const int qrow = qq * 32 + l31;
    bf16x8 aq[4];
    {
        const float* qp = Q + bo + (size_t)qrow * DH + hi * 8;
        #pragma unroll
        for (int st = 0; st < 4; ++st) {
            f32x4 a = *(const f32x4*)(qp + st * 16);
            f32x4 c = *(const f32x4*)(qp + st * 16 + 4);
            #pragma unroll
            for (int j = 0; j < 4; ++j) {
                aq[st][j]     = f2bf(a[j] * SCLQ);
                aq[st][j + 4] = f2bf(c[j] * SCLQ);
            }
        }
    }

    f32x16 oacc0, oacc1;
    #pragma unroll
    for (int i = 0; i < 16; ++i) { oacc0[i] = 0.f; oacc1[i] = 0.f; }
    float Lrun = 0.f;

    const int lo8 = lane * 8;

    for (int kt = wave; kt < nkt; kt += 4) {
        const int k0 = kt * BK;
        const short* kf = KFb + (size_t)kt * TILE_SH;
        const short* vf = VFb + (size_t)kt * TILE_SH;

        auto ldA = [&](int f) -> bf16x8 {
            if constexpr (PRE) {
                return *(const bf16x8*)(kf + f * FRAG + lo8);
            } else {
                const int st = f >> 1, kh = f & 1;
                const float* p = Kf32 + (size_t)(k0 + kh * 32 + l31) * DH + st * 16 + hi * 8;
                f32x4 x = *(const f32x4*)p;
                f32x4 y = *(const f32x4*)(p + 4);
                bf16x8 rr;
                #pragma unroll
                for (int j = 0; j < 4; ++j) { rr[j] = f2bf(x[j]); rr[j + 4] = f2bf(y[j]); }
                return rr;
            }
        };
        auto ldV = [&](int f) -> bf16x8 {
            if constexpr (PRE) {
                return *(const bf16x8*)(vf + f * FRAG + lo8);
            } else {
                const int ks = f >> 1, dh = f & 1;
                bf16x8 rr;
                #pragma unroll
                for (int j = 0; j < 8; ++j)
                    rr[j] = f2bf(Vf32[(size_t)(k0 + ks * 16 + hi * 8 + j) * DH + dh * 32 + l31]);
                return rr;
            }
        };

        // ---- S^T = K * Q^T : rows = keys, cols = q (l31); staggered loads ----
        f32x16 s0, s1;
        #pragma unroll
        for (int i = 0; i < 16; ++i) { s0[i] = 0.f; s1[i] = 0.f; }

        __builtin_amdgcn_s_setprio(1);
        bf16x8 A00 = ldA(0), A01 = ldA(1);
        bf16x8 A10 = ldA(2), A11 = ldA(3);
        s0 = __builtin_amdgcn_mfma_f32_32x32x16_bf16(A00, aq[0], s0, 0, 0, 0);
        s1 = __builtin_amdgcn_mfma_f32_32x32x16_bf16(A01, aq[0], s1, 0, 0, 0);
        bf16x8 A20 = ldA(4), A21 = ldA(5);
        s0 = __builtin_amdgcn_mfma_f32_32x32x16_bf16(A10, aq[1], s0, 0, 0, 0);
        s1 = __builtin_amdgcn_mfma_f32_32x32x16_bf16(A11, aq[1], s1, 0, 0, 0);
        bf16x8 A30 = ldA(6), A31 = ldA(7);
        s0 = __builtin_amdgcn_mfma_f32_32x32x16_bf16(A20, aq[2], s0, 0, 0, 0);
        s1 = __builtin_amdgcn_mfma_f32_32x32x16_bf16(A21, aq[2], s1, 0, 0, 0);
        s0 = __builtin_amdgcn_mfma_f32_32x32x16_bf16(A30, aq[3], s0, 0, 0, 0);
        s1 = __builtin_amdgcn_mfma_f32_32x32x16_bf16(A31, aq[3], s1, 0, 0, 0);
        __builtin_amdgcn_s_setprio(0);

        // early V loads: latency hides under softmax VALU work
        bf16x8 V00 = ldV(0), V01 = ldV(1);
        bf16x8 V10 = ldV(2), V11 = ldV(3);

        // ---- p = exp2(S); mask by key row on boundary tile only ----
        if (k0 + BK <= vl) {
            #pragma unroll
            for (int r = 0; r < 16; ++r) {
                s0[r] = __builtin_amdgcn_exp2f(s0[r]);
                s1[r] = __builtin_amdgcn_exp2f(s1[r]);
            }
        } else {
            #pragma unroll
            for (int r = 0; r < 16; ++r) {
                const int krow = k0 + (r & 3) + 8 * (r >> 2) + 4 * hi;
                s0[r] = (krow < vl)      ? __builtin_amdgcn_exp2f(s0[r]) : 0.f;
                s1[r] = (krow + 32 < vl) ? __builtin_amdgcn_exp2f(s1[r]) : 0.f;
            }
        }

        // ---- l[q=l31] += sum over this tile's keys (VALU + permlane) ----
        {
            float ls = 0.f;
            #pragma unroll
            for (int r = 0; r < 16; ++r) ls += s0[r] + s1[r];
            u32 a = __float_as_uint(ls), c = a;
            pl32swap(a, c);          // own + cross-hi partner, all lanes
            Lrun += __uint_as_float(a) + __uint_as_float(c);
        }

        // ---- pack to bf16 pairs, in-register P exchange -> PV A-frags ----
        u32 pk0[8], pk1[8];
        #pragma unroll
        for (int i = 0; i < 8; ++i) {
            pk0[i] = pk2bf(s0[2 * i], s0[2 * i + 1]);
            pk1[i] = pk2bf(s1[2 * i], s1[2 * i + 1]);
        }
        bf16x8 ap[4];
        #pragma unroll
        for (int t = 0; t < 2; ++t) {
            u32 x0 = pk0[4 * t], x1 = pk0[4 * t + 1];
            u32 x2 = pk0[4 * t + 2], x3 = pk0[4 * t + 3];
            pl32swap(x0, x2); pl32swap(x1, x3);
            u32x4 w; w[0] = x0; w[1] = x1; w[2] = x2; w[3] = x3;
            ap[t] = *(bf16x8*)&w;
            u32 y0 = pk1[4 * t], y1 = pk1[4 * t + 1];
            u32 y2 = pk1[4 * t + 2], y3 = pk1[4 * t + 3];
            pl32swap(y0, y2); pl32swap(y1, y3);
            u32x4 v; v[0] = y0; v[1] = y1; v[2] = y2; v[3] = y3;
            ap[2 + t] = *(bf16x8*)&v;
        }

        // ---- O += P V ----
        __builtin_amdgcn_s_setprio(1);
        oacc0 = __builtin_amdgcn_mfma_f32_32x32x16_bf16(ap[0], V00, oacc0, 0, 0, 0);
        oacc1 = __builtin_amdgcn_mfma_f32_32x32x16_bf16(ap[0], V01, oacc1, 0, 0, 0);
        bf16x8 V20 = ldV(4), V21 = ldV(5);
        oacc0 = __builtin_amdgcn_mfma_f32_32x32x16_bf16(ap[1], V10, oacc0, 0, 0, 0);
        oacc1 = __builtin_amdgcn_mfma_f32_32x32x16_bf16(ap[1], V11, oacc1, 0, 0, 0);
        bf16x8 V30 = ldV(6), V31 = ldV(7);
        oacc0 = __builtin_amdgcn_mfma_f32_32x32x16_bf16(ap[2], V20, oacc0, 0, 0, 0);
        oacc1 = __builtin_amdgcn_mfma_f32_32x32x16_bf16(ap[2], V21, oacc1, 0, 0, 0);
        oacc0 = __builtin_amdgcn_mfma_f32_32x32x16_bf16(ap[3], V30, oacc0, 0, 0, 0);
        oacc1 = __builtin_amdgcn_mfma_f32_32x32x16_bf16(ap[3], V31, oacc1, 0, 0, 0);
        __builtin_amdgcn_s_setprio(0);
    }

    // ---- in-block 2-round tree combine of the 4 wave partials ----
    // round 1: waves 1,3 dump; waves 0,2 add.
    if (wave & 1) {
        float* rp = &Red[wave >> 1][lane][0];
        #pragma unroll
        for (int wd = 0; wd < 4; ++wd) {
            f32x4 t0, t1;
            #pragma unroll
            for (int i = 0; i < 4; ++i) { t0[i] = oacc0[wd * 4 + i]; t1[i] = oacc1[wd * 4 + i]; }
            *(f32x4*)(rp + wd * 4)      = t0;
            *(f32x4*)(rp + 16 + wd * 4) = t1;
        }
        rp[32] = Lrun;
    }
    __syncthreads();
    if (!(wave & 1)) {
        const float* rp = &Red[wave >> 1][lane][0];
        #pragma unroll
        for (int wd = 0; wd < 4; ++wd) {
            f32x4 t0 = *(const f32x4*)(rp + wd * 4);
            f32x4 t1 = *(const f32x4*)(rp + 16 + wd * 4);
            #pragma unroll
            for (int i = 0; i < 4; ++i) { oacc0[wd * 4 + i] += t0[i]; oacc1[wd * 4 + i] += t1[i]; }
        }
        Lrun += rp[32];
    }
    __syncthreads();
    // round 2: wave 2 dumps; wave 0 adds + writes O.
    if (wave == 2) {
        float* rp = &Red[0][lane][0];
        #pragma unroll
        for (int wd = 0; wd < 4; ++wd) {
            f32x4 t0, t1;
            #pragma unroll
            for (int i = 0; i < 4; ++i) { t0[i] = oacc0[wd * 4 + i]; t1[i] = oacc1[wd * 4 + i]; }
            *(f32x4*)(rp + wd * 4)      = t0;
            *(f32x4*)(rp + 16 + wd * 4) = t1;
        }
        rp[32] = Lrun;
    }
    __syncthreads();
    if (wave == 0) {
        const float* rp = &Red[0][lane][0];
        #pragma unroll
        for (int wd = 0; wd < 4; ++wd) {
            f32x4 t0 = *(const f32x4*)(rp + wd * 4);
            f32x4 t1 = *(const f32x4*)(rp + 16 + wd * 4);
            #pragma unroll
            for (int i = 0; i < 4; ++i) { oacc0[wd * 4 + i] += t0[i]; oacc1[wd * 4 + i] += t1[i]; }
        }
        const float Lq = Lrun + rp[32];
        #pragma unroll
        for (int r = 0; r < 16; ++r) {
            const int rb = (r & 3) + 8 * (r >> 2) + 4 * hi;
            const float inv = 1.0f / __shfl(Lq, rb);
            const int row = qq * 32 + rb;
            O[bo + (size_t)row * DH + l31]      = oacc0[r] * inv;
            O[bo + (size_t)row * DH + 32 + l31] = oacc1[r] * inv;
        }
    }
}

extern "C" void kernel_launch(void* const* d_in, const int* in_sizes, int n_in,
                              void* d_out, int out_size, void* d_ws, size_t ws_size,
                              hipStream_t stream) {
    const float* Q  = (const float*)d_in[0];
    const float* K  = (const float*)d_in[1];
    const float* V  = (const float*)d_in[2];
    const int*   VL = (const int*)d_in[3];
    float* O = (float*)d_out;

    const size_t nel  = (size_t)32 * 32 * TILE_SH;   // shorts per frag array
    const size_t need = 2 * nel * sizeof(short);     // 16 MB (ws >= 68MB proven R5)
    if (ws_size >= need) {
        short* KF = (short*)d_ws;
        short* VF = KF + nel;
        prepass<<<dim3(1024), dim3(256), 0, stream>>>(K, V, KF, VF);
        attn_fwd<true><<<dim3(2048), dim3(256), 0, stream>>>(Q, K, V, KF, VF, VL, O);
    } else {
        attn_fwd<false><<<dim3(2048), dim3(256), 0, stream>>>(Q, K, V, nullptr, nullptr, VL, O);
    }
}